// Round 2
// baseline (938.356 us; speedup 1.0000x reference)
//
#include <hip/hip_runtime.h>
#include <cstdint>
#include <cstddef>

#define DI __device__ __forceinline__

typedef __bf16 bf16x8 __attribute__((ext_vector_type(8)));
typedef float f32x4 __attribute__((ext_vector_type(4)));
typedef unsigned short u16x8 __attribute__((ext_vector_type(8)));

constexpr int Bb = 4, Ss = 4096, Cc = 256, Ee = 256;

// fp32 -> bf16 (RNE) bit trick; inputs are finite
DI unsigned bf_hi(float f) {
  unsigned u = __builtin_bit_cast(unsigned, f);
  return (u + 0x7fffu + ((u >> 16) & 1u)) >> 16;
}
DI float bf_f(unsigned h) { return __builtin_bit_cast(float, h << 16); }
// pack element as (hi | lo<<16) where lo = bf16(f - hi)
DI uint32_t hilo_word(float f) {
  unsigned h = bf_hi(f);
  unsigned l = bf_hi(f - bf_f(h));
  return h | (l << 16);
}

DI f32x4 mfma16(bf16x8 a, bf16x8 b, f32x4 c) {
  return __builtin_amdgcn_mfma_f32_16x16x32_bf16(a, b, c, 0, 0, 0);
}

// ---------------- W transpose: wt[mat][n][k] = W[k][n] ----------------
__global__ __launch_bounds__(256) void k_transpose(
    const float* __restrict__ wq, const float* __restrict__ wk,
    const float* __restrict__ wv, float* __restrict__ wt) {
  const float* src = blockIdx.x == 0 ? wq : (blockIdx.x == 1 ? wk : wv);
  float* dst = wt + (size_t)blockIdx.x * Cc * Cc;
  const int n = threadIdx.x;
  for (int k = 0; k < Cc; k++) dst[n * Cc + k] = src[k * Cc + n];
}

// ---------------- fused QKV projection (split-bf16 MFMA) ----------------
// grid (M/64, 256/64, 3), block 256. Writes Q,K as hilo [B*S][C]; V as hilo [B][E][S].
__global__ __launch_bounds__(256, 2) void k_proj(
    const float* __restrict__ x, const float* __restrict__ wt,
    const float* __restrict__ bq, const float* __restrict__ bk,
    const float* __restrict__ bv, uint32_t* __restrict__ qhl,
    uint32_t* __restrict__ khl, uint32_t* __restrict__ vthl) {
  __shared__ __align__(16) unsigned short xh[64 * 64], xl[64 * 64];
  __shared__ __align__(16) unsigned short wh[64 * 64], wl[64 * 64];
  const int t = threadIdx.x, lane = t & 63, wid = t >> 6;
  const int mat = blockIdx.z;
  const int n0 = blockIdx.y * 64, m0 = blockIdx.x * 64;
  const float* wm = wt + (size_t)mat * Cc * Cc;
  const float* bias = mat == 0 ? bq : (mat == 1 ? bk : bv);

  f32x4 acc[4];
#pragma unroll
  for (int f = 0; f < 4; f++) acc[f] = (f32x4){0.f, 0.f, 0.f, 0.f};

  const int srow = t >> 2, scol = (t & 3) * 16;

  for (int k0 = 0; k0 < Cc; k0 += 64) {
    const float* xs = x + (size_t)(m0 + srow) * Cc + k0 + scol;
    const float* wsrc = wm + (size_t)(n0 + srow) * Cc + k0 + scol;
#pragma unroll
    for (int j = 0; j < 16; j += 4) {
      const int off = srow * 128 + (((scol + j) * 2) ^ ((srow & 7) << 4));
      {
        float4 v = *(const float4*)(xs + j);
        unsigned h0 = bf_hi(v.x), h1 = bf_hi(v.y), h2 = bf_hi(v.z), h3 = bf_hi(v.w);
        unsigned l0 = bf_hi(v.x - bf_f(h0)), l1 = bf_hi(v.y - bf_f(h1));
        unsigned l2 = bf_hi(v.z - bf_f(h2)), l3 = bf_hi(v.w - bf_f(h3));
        *(uint2*)((char*)xh + off) = make_uint2(h0 | (h1 << 16), h2 | (h3 << 16));
        *(uint2*)((char*)xl + off) = make_uint2(l0 | (l1 << 16), l2 | (l3 << 16));
      }
      {
        float4 v = *(const float4*)(wsrc + j);
        unsigned h0 = bf_hi(v.x), h1 = bf_hi(v.y), h2 = bf_hi(v.z), h3 = bf_hi(v.w);
        unsigned l0 = bf_hi(v.x - bf_f(h0)), l1 = bf_hi(v.y - bf_f(h1));
        unsigned l2 = bf_hi(v.z - bf_f(h2)), l3 = bf_hi(v.w - bf_f(h3));
        *(uint2*)((char*)wh + off) = make_uint2(h0 | (h1 << 16), h2 | (h3 << 16));
        *(uint2*)((char*)wl + off) = make_uint2(l0 | (l1 << 16), l2 | (l3 << 16));
      }
    }
    __syncthreads();
#pragma unroll
    for (int c2 = 0; c2 < 2; c2++) {
      const int arow = wid * 16 + (lane & 15);
      const int aby = arow * 128 + ((c2 * 64 + (lane >> 4) * 16) ^ ((arow & 7) << 4));
      bf16x8 ah = *(const bf16x8*)((const char*)xh + aby);
      bf16x8 al = *(const bf16x8*)((const char*)xl + aby);
#pragma unroll
      for (int f = 0; f < 4; f++) {
        const int brow = f * 16 + (lane & 15);
        const int bby = brow * 128 + ((c2 * 64 + (lane >> 4) * 16) ^ ((brow & 7) << 4));
        bf16x8 bh = *(const bf16x8*)((const char*)wh + bby);
        bf16x8 bl = *(const bf16x8*)((const char*)wl + bby);
        acc[f] = mfma16(ah, bh, acc[f]);
        acc[f] = mfma16(al, bh, acc[f]);
        acc[f] = mfma16(ah, bl, acc[f]);
      }
    }
    __syncthreads();
  }

#pragma unroll
  for (int f = 0; f < 4; f++) {
    const int ncol = n0 + f * 16 + (lane & 15);
    const float bb = bias[ncol];
    if (mat == 2) {
      uint32_t wd0, wd1, wd2, wd3;
      wd0 = hilo_word(acc[f][0] + bb);
      wd1 = hilo_word(acc[f][1] + bb);
      wd2 = hilo_word(acc[f][2] + bb);
      wd3 = hilo_word(acc[f][3] + bb);
      const int mg = m0 + wid * 16 + (lane >> 4) * 4;
      const int bidx = mg >> 12, sidx = mg & 4095;
      *(uint4*)(vthl + ((size_t)(bidx * Ee + ncol)) * Ss + sidx) =
          make_uint4(wd0, wd1, wd2, wd3);
    } else {
      uint32_t* dst = (mat == 0 ? qhl : khl);
#pragma unroll
      for (int r = 0; r < 4; r++) {
        const int mg = m0 + wid * 16 + (lane >> 4) * 4 + r;
        dst[(size_t)mg * Cc + ncol] = hilo_word(acc[f][r] + bb);
      }
    }
  }
}

// ---------------- flash attention + sigmoid ----------------
// grid (S/64, B), block 256 (4 waves, 16 q-rows each). KBLK=64.
__global__ __launch_bounds__(256, 1) void k_attn(
    const uint32_t* __restrict__ qhl, const uint32_t* __restrict__ khl,
    const uint32_t* __restrict__ vthl, float* __restrict__ out) {
  __shared__ __align__(16) unsigned short kh[64 * 256], kl[64 * 256];   // 32KB+32KB
  __shared__ __align__(16) unsigned short vh[256 * 64], vl[256 * 64];   // 32KB+32KB
  __shared__ __align__(16) unsigned short ph[4][16 * 64], pl[4][16 * 64]; // 8KB+8KB
  const int t = threadIdx.x, lane = t & 63, w = t >> 6;
  const int b = blockIdx.y, q0 = blockIdx.x * 64;

  // Q fragments in registers (hi/lo)
  bf16x8 qh_[8], ql_[8];
  {
    const int qrow = q0 + w * 16 + (lane & 15);
    const uint32_t* qp = qhl + (size_t)(b * Ss + qrow) * Cc;
#pragma unroll
    for (int c = 0; c < 8; c++) {
      const int kb = c * 32 + (lane >> 4) * 8;
      uint4 a0 = *(const uint4*)(qp + kb);
      uint4 a1 = *(const uint4*)(qp + kb + 4);
      u16x8 hv, lv;
      hv[0] = (unsigned short)a0.x; lv[0] = (unsigned short)(a0.x >> 16);
      hv[1] = (unsigned short)a0.y; lv[1] = (unsigned short)(a0.y >> 16);
      hv[2] = (unsigned short)a0.z; lv[2] = (unsigned short)(a0.z >> 16);
      hv[3] = (unsigned short)a0.w; lv[3] = (unsigned short)(a0.w >> 16);
      hv[4] = (unsigned short)a1.x; lv[4] = (unsigned short)(a1.x >> 16);
      hv[5] = (unsigned short)a1.y; lv[5] = (unsigned short)(a1.y >> 16);
      hv[6] = (unsigned short)a1.z; lv[6] = (unsigned short)(a1.z >> 16);
      hv[7] = (unsigned short)a1.w; lv[7] = (unsigned short)(a1.w >> 16);
      qh_[c] = __builtin_bit_cast(bf16x8, hv);
      ql_[c] = __builtin_bit_cast(bf16x8, lv);
    }
  }

  f32x4 acc[16];
#pragma unroll
  for (int eg = 0; eg < 16; eg++) acc[eg] = (f32x4){0.f, 0.f, 0.f, 0.f};
  float mrun[4] = {-1e30f, -1e30f, -1e30f, -1e30f};
  float lrun[4] = {0.f, 0.f, 0.f, 0.f};

  for (int kt = 0; kt < 64; kt++) {
    // ---- stage K tile (contiguous 64KB) ----
    const uint32_t* ksrc = khl + ((size_t)b * Ss + kt * 64) * Cc;
#pragma unroll
    for (int i = 0; i < 16; i++) {
      const int u = i * 256 + t;
      uint4 v = *(const uint4*)(ksrc + (size_t)u * 4);
      const int row = u >> 6, col = (u & 63) * 4;
      const int off = row * 512 + ((col * 2) ^ ((row & 7) << 4));
      *(uint2*)((char*)kh + off) =
          make_uint2((v.x & 0xffffu) | ((v.y & 0xffffu) << 16),
                     (v.z & 0xffffu) | ((v.w & 0xffffu) << 16));
      *(uint2*)((char*)kl + off) =
          make_uint2((v.x >> 16) | (v.y & 0xffff0000u),
                     (v.z >> 16) | (v.w & 0xffff0000u));
    }
    // ---- stage V^T tile ----
#pragma unroll
    for (int i = 0; i < 16; i++) {
      const int u = i * 256 + t;
      const int erow = u >> 4, col = (u & 15) * 4;
      uint4 v = *(const uint4*)(vthl + ((size_t)b * Ee + erow) * Ss + kt * 64 + col);
      const int off = erow * 128 + ((col * 2) ^ ((erow & 7) << 4));
      *(uint2*)((char*)vh + off) =
          make_uint2((v.x & 0xffffu) | ((v.y & 0xffffu) << 16),
                     (v.z & 0xffffu) | ((v.w & 0xffffu) << 16));
      *(uint2*)((char*)vl + off) =
          make_uint2((v.x >> 16) | (v.y & 0xffff0000u),
                     (v.z >> 16) | (v.w & 0xffff0000u));
    }
    __syncthreads();

    // ---- S = Q K^T (3-term split) ----
    f32x4 sacc[4];
#pragma unroll
    for (int f = 0; f < 4; f++) sacc[f] = (f32x4){0.f, 0.f, 0.f, 0.f};
#pragma unroll
    for (int c = 0; c < 8; c++) {
#pragma unroll
      for (int f = 0; f < 4; f++) {
        const int krow = f * 16 + (lane & 15);
        const int kby = krow * 512 + ((c * 64 + (lane >> 4) * 16) ^ ((krow & 7) << 4));
        bf16x8 bh = *(const bf16x8*)((const char*)kh + kby);
        bf16x8 bl = *(const bf16x8*)((const char*)kl + kby);
        sacc[f] = mfma16(qh_[c], bh, sacc[f]);
        sacc[f] = mfma16(ql_[c], bh, sacc[f]);
        sacc[f] = mfma16(qh_[c], bl, sacc[f]);
      }
    }

    // ---- online softmax (rows = (lane>>4)*4+r, cols across lane&15 and f) ----
    float rmax[4], mnew[4], sc[4], rsum[4];
#pragma unroll
    for (int r = 0; r < 4; r++)
      rmax[r] = fmaxf(fmaxf(sacc[0][r], sacc[1][r]), fmaxf(sacc[2][r], sacc[3][r]));
#pragma unroll
    for (int r = 0; r < 4; r++) {
      rmax[r] = fmaxf(rmax[r], __shfl_xor(rmax[r], 1, 64));
      rmax[r] = fmaxf(rmax[r], __shfl_xor(rmax[r], 2, 64));
      rmax[r] = fmaxf(rmax[r], __shfl_xor(rmax[r], 4, 64));
      rmax[r] = fmaxf(rmax[r], __shfl_xor(rmax[r], 8, 64));
      mnew[r] = fmaxf(mrun[r], rmax[r]);
      sc[r] = __expf(mrun[r] - mnew[r]);
      mrun[r] = mnew[r];
      rsum[r] = 0.f;
    }
#pragma unroll
    for (int f = 0; f < 4; f++) {
#pragma unroll
      for (int r = 0; r < 4; r++) {
        float p = __expf(sacc[f][r] - mnew[r]);
        sacc[f][r] = p;
        rsum[r] += p;
      }
    }
#pragma unroll
    for (int r = 0; r < 4; r++) {
      rsum[r] += __shfl_xor(rsum[r], 1, 64);
      rsum[r] += __shfl_xor(rsum[r], 2, 64);
      rsum[r] += __shfl_xor(rsum[r], 4, 64);
      rsum[r] += __shfl_xor(rsum[r], 8, 64);
      lrun[r] = lrun[r] * sc[r] + rsum[r];
    }
    // ---- P -> per-wave LDS (hi/lo, swizzled) ----
#pragma unroll
    for (int f = 0; f < 4; f++) {
#pragma unroll
      for (int r = 0; r < 4; r++) {
        float p = sacc[f][r];
        unsigned hb = bf_hi(p);
        unsigned lb = bf_hi(p - bf_f(hb));
        const int prow = (lane >> 4) * 4 + r, pcol = f * 16 + (lane & 15);
        const int off = prow * 128 + ((pcol * 2) ^ ((prow & 7) << 4));
        *(unsigned short*)((char*)ph[w] + off) = (unsigned short)hb;
        *(unsigned short*)((char*)pl[w] + off) = (unsigned short)lb;
      }
    }
    // ---- rescale O ----
#pragma unroll
    for (int eg = 0; eg < 16; eg++) {
      acc[eg][0] *= sc[0]; acc[eg][1] *= sc[1];
      acc[eg][2] *= sc[2]; acc[eg][3] *= sc[3];
    }
    // ---- O += P V (3-term split) ----
#pragma unroll
    for (int ch = 0; ch < 2; ch++) {
      const int prow = lane & 15;
      const int pby = prow * 128 + ((ch * 64 + (lane >> 4) * 16) ^ ((prow & 7) << 4));
      bf16x8 pa_h = *(const bf16x8*)((const char*)ph[w] + pby);
      bf16x8 pa_l = *(const bf16x8*)((const char*)pl[w] + pby);
#pragma unroll
      for (int eg = 0; eg < 16; eg++) {
        const int erow = eg * 16 + (lane & 15);
        const int vby = erow * 128 + ((ch * 64 + (lane >> 4) * 16) ^ ((erow & 7) << 4));
        bf16x8 bvh = *(const bf16x8*)((const char*)vh + vby);
        bf16x8 bvl = *(const bf16x8*)((const char*)vl + vby);
        acc[eg] = mfma16(pa_h, bvh, acc[eg]);
        acc[eg] = mfma16(pa_l, bvh, acc[eg]);
        acc[eg] = mfma16(pa_h, bvl, acc[eg]);
      }
    }
    __syncthreads();
  }

  // ---- epilogue: normalize + sigmoid ----
  const int qbase = q0 + w * 16 + (lane >> 4) * 4;
#pragma unroll
  for (int eg = 0; eg < 16; eg++) {
    const int e = eg * 16 + (lane & 15);
#pragma unroll
    for (int r = 0; r < 4; r++) {
      float v = acc[eg][r] / lrun[r];
      out[((size_t)(b * Ss + qbase + r)) * Ee + e] = 1.f / (1.f + __expf(-v));
    }
  }
}

extern "C" void kernel_launch(void* const* d_in, const int* in_sizes, int n_in,
                              void* d_out, int out_size, void* d_ws, size_t ws_size,
                              hipStream_t stream) {
  (void)in_sizes; (void)n_in; (void)out_size; (void)ws_size;
  const float* x  = (const float*)d_in[0];
  const float* Wq = (const float*)d_in[1];
  const float* bq = (const float*)d_in[2];
  const float* Wk = (const float*)d_in[3];
  const float* bk = (const float*)d_in[4];
  const float* Wv = (const float*)d_in[5];
  const float* bv = (const float*)d_in[6];
  float* out = (float*)d_out;

  char* ws = (char*)d_ws;
  float* wt       = (float*)ws;                         // 768 KB: [3][256][256] W^T
  uint32_t* qhl   = (uint32_t*)(ws + (size_t)1  * (1u << 20));  // 16 MB Q hilo [B*S][C]
  uint32_t* khl   = (uint32_t*)(ws + (size_t)17 * (1u << 20));  // 16 MB K hilo [B*S][C]
  uint32_t* vthl  = (uint32_t*)(ws + (size_t)33 * (1u << 20));  // 16 MB V^T hilo [B][E][S]

  hipLaunchKernelGGL(k_transpose, dim3(3), dim3(256), 0, stream, Wq, Wk, Wv, wt);
  hipLaunchKernelGGL(k_proj, dim3(256, 4, 3), dim3(256), 0, stream,
                     x, wt, bq, bk, bv, qhl, khl, vthl);
  hipLaunchKernelGGL(k_attn, dim3(64, 4), dim3(256), 0, stream, qhl, khl, vthl, out);
}

// Round 3
// 567.930 us; speedup vs baseline: 1.6522x; 1.6522x over previous
//
#include <hip/hip_runtime.h>
#include <cstdint>
#include <cstddef>

#define DI __device__ __forceinline__

typedef __bf16 bf16x8 __attribute__((ext_vector_type(8)));
typedef float f32x4 __attribute__((ext_vector_type(4)));

constexpr int Bb = 4, Ss = 4096, Cc = 256, Ee = 256;

// fp32 -> bf16 (RNE) bit trick; inputs are finite
DI unsigned bf_hi(float f) {
  unsigned u = __builtin_bit_cast(unsigned, f);
  return (u + 0x7fffu + ((u >> 16) & 1u)) >> 16;
}
DI float bf_f(unsigned h) { return __builtin_bit_cast(float, h << 16); }

DI f32x4 mfma16(bf16x8 a, bf16x8 b, f32x4 c) {
  return __builtin_amdgcn_mfma_f32_16x16x32_bf16(a, b, c, 0, 0, 0);
}

// async global->LDS, 16B per lane. LDS dest must be wave-uniform base; global
// src is per-lane (pre-swizzled).  [guide §5 / m97 / m173]
DI void gl16(const void* g, void* l) {
  __builtin_amdgcn_global_load_lds(
      (const __attribute__((address_space(1))) unsigned*)g,
      (__attribute__((address_space(3))) unsigned*)l, 16, 0, 0);
}

// ---------------- W transpose: wt[mat][n][k] = W[k][n] ----------------
__global__ __launch_bounds__(256) void k_transpose(
    const float* __restrict__ wq, const float* __restrict__ wk,
    const float* __restrict__ wv, float* __restrict__ wt) {
  const float* src = blockIdx.x == 0 ? wq : (blockIdx.x == 1 ? wk : wv);
  float* dst = wt + (size_t)blockIdx.x * Cc * Cc;
  const int n = threadIdx.x;
  for (int k = 0; k < Cc; k++) dst[n * Cc + k] = src[k * Cc + n];
}

// ---------------- fused QKV projection (split-bf16 MFMA) ----------------
// grid (M/64, 256/64, 3), block 256. Writes split hi/lo arrays:
// Q,K: [B*S][C] u16; V^T: [B][E][S] u16.
__global__ __launch_bounds__(256, 2) void k_proj(
    const float* __restrict__ x, const float* __restrict__ wt,
    const float* __restrict__ bq, const float* __restrict__ bk,
    const float* __restrict__ bv,
    unsigned short* __restrict__ qhi, unsigned short* __restrict__ qlo,
    unsigned short* __restrict__ khi, unsigned short* __restrict__ klo,
    unsigned short* __restrict__ vthi, unsigned short* __restrict__ vtlo) {
  __shared__ __align__(16) unsigned short xh[64 * 64], xl[64 * 64];
  __shared__ __align__(16) unsigned short wh[64 * 64], wl[64 * 64];
  const int t = threadIdx.x, lane = t & 63, wid = t >> 6;
  const int mat = blockIdx.z;
  const int n0 = blockIdx.y * 64, m0 = blockIdx.x * 64;
  const float* wm = wt + (size_t)mat * Cc * Cc;
  const float* bias = mat == 0 ? bq : (mat == 1 ? bk : bv);

  f32x4 acc[4];
#pragma unroll
  for (int f = 0; f < 4; f++) acc[f] = (f32x4){0.f, 0.f, 0.f, 0.f};

  const int srow = t >> 2, scol = (t & 3) * 16;

  for (int k0 = 0; k0 < Cc; k0 += 64) {
    const float* xs = x + (size_t)(m0 + srow) * Cc + k0 + scol;
    const float* wsrc = wm + (size_t)(n0 + srow) * Cc + k0 + scol;
#pragma unroll
    for (int j = 0; j < 16; j += 4) {
      const int off = srow * 128 + (((scol + j) * 2) ^ ((srow & 7) << 4));
      {
        float4 v = *(const float4*)(xs + j);
        unsigned h0 = bf_hi(v.x), h1 = bf_hi(v.y), h2 = bf_hi(v.z), h3 = bf_hi(v.w);
        unsigned l0 = bf_hi(v.x - bf_f(h0)), l1 = bf_hi(v.y - bf_f(h1));
        unsigned l2 = bf_hi(v.z - bf_f(h2)), l3 = bf_hi(v.w - bf_f(h3));
        *(uint2*)((char*)xh + off) = make_uint2(h0 | (h1 << 16), h2 | (h3 << 16));
        *(uint2*)((char*)xl + off) = make_uint2(l0 | (l1 << 16), l2 | (l3 << 16));
      }
      {
        float4 v = *(const float4*)(wsrc + j);
        unsigned h0 = bf_hi(v.x), h1 = bf_hi(v.y), h2 = bf_hi(v.z), h3 = bf_hi(v.w);
        unsigned l0 = bf_hi(v.x - bf_f(h0)), l1 = bf_hi(v.y - bf_f(h1));
        unsigned l2 = bf_hi(v.z - bf_f(h2)), l3 = bf_hi(v.w - bf_f(h3));
        *(uint2*)((char*)wh + off) = make_uint2(h0 | (h1 << 16), h2 | (h3 << 16));
        *(uint2*)((char*)wl + off) = make_uint2(l0 | (l1 << 16), l2 | (l3 << 16));
      }
    }
    __syncthreads();
#pragma unroll
    for (int c2 = 0; c2 < 2; c2++) {
      const int arow = wid * 16 + (lane & 15);
      const int aby = arow * 128 + ((c2 * 64 + (lane >> 4) * 16) ^ ((arow & 7) << 4));
      bf16x8 ah = *(const bf16x8*)((const char*)xh + aby);
      bf16x8 al = *(const bf16x8*)((const char*)xl + aby);
#pragma unroll
      for (int f = 0; f < 4; f++) {
        const int brow = f * 16 + (lane & 15);
        const int bby = brow * 128 + ((c2 * 64 + (lane >> 4) * 16) ^ ((brow & 7) << 4));
        bf16x8 bh = *(const bf16x8*)((const char*)wh + bby);
        bf16x8 bl = *(const bf16x8*)((const char*)wl + bby);
        acc[f] = mfma16(ah, bh, acc[f]);
        acc[f] = mfma16(al, bh, acc[f]);
        acc[f] = mfma16(ah, bl, acc[f]);
      }
    }
    __syncthreads();
  }

#pragma unroll
  for (int f = 0; f < 4; f++) {
    const int ncol = n0 + f * 16 + (lane & 15);
    const float bb = bias[ncol];
    if (mat == 2) {
      unsigned h[4], l[4];
#pragma unroll
      for (int r = 0; r < 4; r++) {
        float v = acc[f][r] + bb;
        h[r] = bf_hi(v);
        l[r] = bf_hi(v - bf_f(h[r]));
      }
      const int mg = m0 + wid * 16 + (lane >> 4) * 4;
      const int bidx = mg >> 12, sidx = mg & 4095;
      const size_t base = ((size_t)(bidx * Ee + ncol)) * Ss + sidx;
      *(uint2*)(vthi + base) = make_uint2(h[0] | (h[1] << 16), h[2] | (h[3] << 16));
      *(uint2*)(vtlo + base) = make_uint2(l[0] | (l[1] << 16), l[2] | (l[3] << 16));
    } else {
      unsigned short* dh = (mat == 0 ? qhi : khi);
      unsigned short* dl = (mat == 0 ? qlo : klo);
#pragma unroll
      for (int r = 0; r < 4; r++) {
        const int mg = m0 + wid * 16 + (lane >> 4) * 4 + r;
        float v = acc[f][r] + bb;
        unsigned h = bf_hi(v);
        dh[(size_t)mg * Cc + ncol] = (unsigned short)h;
        dl[(size_t)mg * Cc + ncol] = (unsigned short)bf_hi(v - bf_f(h));
      }
    }
  }
}

// ---------------- flash attention + sigmoid ----------------
// grid (S/64, B), block 512 (8 waves). Wave w: q-group w&3 (16 rows),
// e-half w>>2 (128 cols). QK duplicated per wave-pair. KBLK=32,
// double-buffered K/V staged via async global_load_lds (pre-swizzled src).
__global__ __launch_bounds__(512, 2) void k_attn(
    const unsigned short* __restrict__ qhi, const unsigned short* __restrict__ qlo,
    const unsigned short* __restrict__ khi, const unsigned short* __restrict__ klo,
    const unsigned short* __restrict__ vthi, const unsigned short* __restrict__ vtlo,
    float* __restrict__ out) {
  __shared__ __align__(16) unsigned short sKh[2][32 * 256], sKl[2][32 * 256]; // 4x16KB
  __shared__ __align__(16) unsigned short sVh[2][256 * 32], sVl[2][256 * 32]; // 4x16KB
  __shared__ __align__(16) unsigned short sPh[8][16 * 32], sPl[8][16 * 32];   // 16KB
  const int t = threadIdx.x, lane = t & 63, w = t >> 6;
  const int qg = w & 3, eh = w >> 2;
  const int b = blockIdx.y, q0 = blockIdx.x * 64;

  // ---- Q fragments in registers (hi/lo), direct from split arrays ----
  bf16x8 qh_[8], ql_[8];
  {
    const int qrow = q0 + qg * 16 + (lane & 15);
    const unsigned short* qph = qhi + (size_t)(b * Ss + qrow) * Cc;
    const unsigned short* qpl = qlo + (size_t)(b * Ss + qrow) * Cc;
#pragma unroll
    for (int c = 0; c < 8; c++) {
      const int kb = c * 32 + (lane >> 4) * 8;
      qh_[c] = *(const bf16x8*)(qph + kb);
      ql_[c] = *(const bf16x8*)(qpl + kb);
    }
  }

  // ---- precompute per-lane pre-swizzled staging source bases ----
  // K tile: 32 rows x 512B (256 bf16).  chunk j: LDS off o=(w*2+j)*1024+lane*16
  // V tile: 256 rows x 64B (32 bf16).
  const char* kbh[2]; const char* kbl[2]; const char* vbh[2]; const char* vbl[2];
#pragma unroll
  for (int j = 0; j < 2; j++) {
    const int o = (w * 2 + j) * 1024 + lane * 16;
    {
      const int row = o >> 9, y = o & 511;
      const size_t src = (size_t)(b * Ss + row) * 512 + (size_t)(y ^ ((row & 7) << 4));
      kbh[j] = (const char*)khi + src;
      kbl[j] = (const char*)klo + src;
    }
    {
      const int row = o >> 6, y = o & 63;
      const size_t src = (size_t)(b * Ee + row) * (Ss * 2) + (size_t)(y ^ ((row & 3) << 4));
      vbh[j] = (const char*)vthi + src;
      vbl[j] = (const char*)vtlo + src;
    }
  }
  const int coff = (w * 2) * 1024;  // this wave's LDS byte offset (2KB, j via +1024)

  f32x4 acc[8];
#pragma unroll
  for (int eg = 0; eg < 8; eg++) acc[eg] = (f32x4){0.f, 0.f, 0.f, 0.f};
  float mrun[4] = {-1e30f, -1e30f, -1e30f, -1e30f};
  float lrun[4] = {0.f, 0.f, 0.f, 0.f};

  // ---- prologue: stage tile 0 into buf 0 ----
#pragma unroll
  for (int j = 0; j < 2; j++) {
    gl16(kbh[j], (char*)&sKh[0][0] + coff + j * 1024);
    gl16(kbl[j], (char*)&sKl[0][0] + coff + j * 1024);
    gl16(vbh[j], (char*)&sVh[0][0] + coff + j * 1024);
    gl16(vbl[j], (char*)&sVl[0][0] + coff + j * 1024);
  }
  __syncthreads();  // compiler drains vmcnt before barrier -> buf0 ready

  for (int kt = 0; kt < 128; kt++) {
    const int cur = kt & 1;
    // ---- issue prefetch for kt+1 into buf cur^1 (drains at end barrier) ----
    if (kt + 1 < 128) {
      const size_t ko = (size_t)(kt + 1) * 16384;  // 32 rows * 512B
      const size_t vo = (size_t)(kt + 1) * 64;     // 32 cols * 2B per row
      const int bn = cur ^ 1;
#pragma unroll
      for (int j = 0; j < 2; j++) {
        gl16(kbh[j] + ko, (char*)&sKh[bn][0] + coff + j * 1024);
        gl16(kbl[j] + ko, (char*)&sKl[bn][0] + coff + j * 1024);
        gl16(vbh[j] + vo, (char*)&sVh[bn][0] + coff + j * 1024);
        gl16(vbl[j] + vo, (char*)&sVl[bn][0] + coff + j * 1024);
      }
    }

    // ---- S = Q K^T (3-term split), 32 key rows ----
    const char* kh = (const char*)&sKh[cur][0];
    const char* kl = (const char*)&sKl[cur][0];
    f32x4 sacc[2];
    sacc[0] = (f32x4){0.f, 0.f, 0.f, 0.f};
    sacc[1] = (f32x4){0.f, 0.f, 0.f, 0.f};
#pragma unroll
    for (int c = 0; c < 8; c++) {
#pragma unroll
      for (int f = 0; f < 2; f++) {
        const int krow = f * 16 + (lane & 15);
        const int kby = krow * 512 + ((c * 64 + (lane >> 4) * 16) ^ ((krow & 7) << 4));
        bf16x8 bh = *(const bf16x8*)(kh + kby);
        bf16x8 bl = *(const bf16x8*)(kl + kby);
        sacc[f] = mfma16(qh_[c], bh, sacc[f]);
        sacc[f] = mfma16(ql_[c], bh, sacc[f]);
        sacc[f] = mfma16(qh_[c], bl, sacc[f]);
      }
    }

    // ---- online softmax (rows = (lane>>4)*4+r, cols = lane&15 + f*16) ----
    float rmax[4], mnew[4], sc[4], rsum[4];
#pragma unroll
    for (int r = 0; r < 4; r++) rmax[r] = fmaxf(sacc[0][r], sacc[1][r]);
#pragma unroll
    for (int r = 0; r < 4; r++) {
      rmax[r] = fmaxf(rmax[r], __shfl_xor(rmax[r], 1, 64));
      rmax[r] = fmaxf(rmax[r], __shfl_xor(rmax[r], 2, 64));
      rmax[r] = fmaxf(rmax[r], __shfl_xor(rmax[r], 4, 64));
      rmax[r] = fmaxf(rmax[r], __shfl_xor(rmax[r], 8, 64));
      mnew[r] = fmaxf(mrun[r], rmax[r]);
      sc[r] = __expf(mrun[r] - mnew[r]);
      mrun[r] = mnew[r];
      rsum[r] = 0.f;
    }
#pragma unroll
    for (int f = 0; f < 2; f++) {
#pragma unroll
      for (int r = 0; r < 4; r++) {
        float p = __expf(sacc[f][r] - mnew[r]);
        sacc[f][r] = p;
        rsum[r] += p;
      }
    }
#pragma unroll
    for (int r = 0; r < 4; r++) {
      rsum[r] += __shfl_xor(rsum[r], 1, 64);
      rsum[r] += __shfl_xor(rsum[r], 2, 64);
      rsum[r] += __shfl_xor(rsum[r], 4, 64);
      rsum[r] += __shfl_xor(rsum[r], 8, 64);
      lrun[r] = lrun[r] * sc[r] + rsum[r];
    }

    // ---- P -> own per-wave LDS buffer (hi/lo, swizzled) ----
#pragma unroll
    for (int f = 0; f < 2; f++) {
#pragma unroll
      for (int r = 0; r < 4; r++) {
        float p = sacc[f][r];
        unsigned hb = bf_hi(p);
        unsigned lb = bf_hi(p - bf_f(hb));
        const int prow = (lane >> 4) * 4 + r, pcol = f * 16 + (lane & 15);
        const int off = prow * 64 + ((pcol * 2) ^ ((prow & 3) << 4));
        *(unsigned short*)((char*)sPh[w] + off) = (unsigned short)hb;
        *(unsigned short*)((char*)sPl[w] + off) = (unsigned short)lb;
      }
    }

    // ---- rescale O ----
#pragma unroll
    for (int eg = 0; eg < 8; eg++) {
      acc[eg][0] *= sc[0]; acc[eg][1] *= sc[1];
      acc[eg][2] *= sc[2]; acc[eg][3] *= sc[3];
    }

    // ---- O += P V (3-term split), this wave's e-half ----
    {
      const int pby = (lane & 15) * 64 + (((lane >> 4) * 16) ^ (((lane & 15) & 3) << 4));
      bf16x8 pa_h = *(const bf16x8*)((const char*)sPh[w] + pby);
      bf16x8 pa_l = *(const bf16x8*)((const char*)sPl[w] + pby);
      const char* vh = (const char*)&sVh[cur][0];
      const char* vl = (const char*)&sVl[cur][0];
#pragma unroll
      for (int eg = 0; eg < 8; eg++) {
        const int erow = eh * 128 + eg * 16 + (lane & 15);
        const int vby = erow * 64 + (((lane >> 4) * 16) ^ ((erow & 3) << 4));
        bf16x8 bvh = *(const bf16x8*)(vh + vby);
        bf16x8 bvl = *(const bf16x8*)(vl + vby);
        acc[eg] = mfma16(pa_h, bvh, acc[eg]);
        acc[eg] = mfma16(pa_l, bvh, acc[eg]);
        acc[eg] = mfma16(pa_h, bvl, acc[eg]);
      }
    }
    __syncthreads();  // orders: buf reads done + prefetch (vmcnt drain) landed
  }

  // ---- epilogue: normalize + sigmoid ----
  const int qbase = q0 + qg * 16 + (lane >> 4) * 4;
#pragma unroll
  for (int eg = 0; eg < 8; eg++) {
    const int e = eh * 128 + eg * 16 + (lane & 15);
#pragma unroll
    for (int r = 0; r < 4; r++) {
      float v = acc[eg][r] / lrun[r];
      out[((size_t)(b * Ss + qbase + r)) * Ee + e] = 1.f / (1.f + __expf(-v));
    }
  }
}

extern "C" void kernel_launch(void* const* d_in, const int* in_sizes, int n_in,
                              void* d_out, int out_size, void* d_ws, size_t ws_size,
                              hipStream_t stream) {
  (void)in_sizes; (void)n_in; (void)out_size; (void)ws_size;
  const float* x  = (const float*)d_in[0];
  const float* Wq = (const float*)d_in[1];
  const float* bq = (const float*)d_in[2];
  const float* Wk = (const float*)d_in[3];
  const float* bk = (const float*)d_in[4];
  const float* Wv = (const float*)d_in[5];
  const float* bv = (const float*)d_in[6];
  float* out = (float*)d_out;

  char* ws = (char*)d_ws;
  float* wt = (float*)ws;  // 768 KB: [3][256][256] W^T
  const size_t MB = 1u << 20;
  unsigned short* qhi  = (unsigned short*)(ws + 1 * MB);   // 8 MB each
  unsigned short* qlo  = (unsigned short*)(ws + 9 * MB);
  unsigned short* khi  = (unsigned short*)(ws + 17 * MB);
  unsigned short* klo  = (unsigned short*)(ws + 25 * MB);
  unsigned short* vthi = (unsigned short*)(ws + 33 * MB);  // [B][E][S]
  unsigned short* vtlo = (unsigned short*)(ws + 41 * MB);

  hipLaunchKernelGGL(k_transpose, dim3(3), dim3(256), 0, stream, Wq, Wk, Wv, wt);
  hipLaunchKernelGGL(k_proj, dim3(256, 4, 3), dim3(256), 0, stream,
                     x, wt, bq, bk, bv, qhi, qlo, khi, klo, vthi, vtlo);
  hipLaunchKernelGGL(k_attn, dim3(64, 4), dim3(512), 0, stream,
                     qhi, qlo, khi, klo, vthi, vtlo, out);
}

// Round 4
// 349.842 us; speedup vs baseline: 2.6822x; 1.6234x over previous
//
#include <hip/hip_runtime.h>
#include <cstdint>
#include <cstddef>

#define DI __device__ __forceinline__

typedef __bf16 bf16x8 __attribute__((ext_vector_type(8)));
typedef float f32x4 __attribute__((ext_vector_type(4)));

constexpr int Bb = 4, Ss = 4096, Cc = 256, Ee = 256;

// ---- ws layout (bytes) — total exactly 49 MiB (proven safe in r3) ----
constexpr size_t OFF_QHI = 786432;            // 8 MiB  [B*S][C] u16
constexpr size_t OFF_QLO = 9175040;           // 8 MiB
constexpr size_t OFF_KHI = 17563648;          // 8 MiB  [B][128 kt][16KB image]
constexpr size_t OFF_KLO = 25952256;          // 8 MiB
constexpr size_t OFF_VHI = 34340864;          // 8 MiB  [B][128 kt][16KB image]
constexpr size_t OFF_PML = 42729472;          // 256 KiB [z][b][qt][2][64] f32
constexpr size_t OFF_P1  = 42991616;          // 8 MiB  [b][qt][64][256] bf16

DI unsigned bf_hi(float f) {
  unsigned u = __builtin_bit_cast(unsigned, f);
  return (u + 0x7fffu + ((u >> 16) & 1u)) >> 16;
}
DI float bf_f(unsigned h) { return __builtin_bit_cast(float, h << 16); }

DI f32x4 mfma16(bf16x8 a, bf16x8 b, f32x4 c) {
  return __builtin_amdgcn_mfma_f32_16x16x32_bf16(a, b, c, 0, 0, 0);
}

DI void gl16(const void* g, void* l) {
  __builtin_amdgcn_global_load_lds(
      (const __attribute__((address_space(1))) unsigned*)g,
      (__attribute__((address_space(3))) unsigned*)l, 16, 0, 0);
}

// K image: [32 rows][512B], byte = row*512 + ((col*2) ^ ((row&7)<<4))
// V image: [256 e][64B] packed 2 rows per 128B:
//   byte = (e>>1)*128 + (((e&1)*64 + k*2) ^ (((e>>1)&7)<<4))

// ---------------- W transpose ----------------
__global__ __launch_bounds__(256) void k_transpose(
    const float* __restrict__ wq, const float* __restrict__ wk,
    const float* __restrict__ wv, float* __restrict__ wt) {
  const float* src = blockIdx.x == 0 ? wq : (blockIdx.x == 1 ? wk : wv);
  float* dst = wt + (size_t)blockIdx.x * Cc * Cc;
  const int n = threadIdx.x;
  for (int k = 0; k < Cc; k++) dst[n * Cc + k] = src[k * Cc + n];
}

// ---------------- fused QKV projection ----------------
// grid (256, 4, 3), block 256. Q: linear hi/lo. K: swizzled images hi/lo.
// V: swizzled image hi only.
__global__ __launch_bounds__(256, 2) void k_proj(
    const float* __restrict__ x, const float* __restrict__ wt,
    const float* __restrict__ bq, const float* __restrict__ bk,
    const float* __restrict__ bv, char* __restrict__ ws) {
  __shared__ __align__(16) unsigned short xh[64 * 64], xl[64 * 64];
  __shared__ __align__(16) unsigned short wh[64 * 64], wl[64 * 64];
  const int t = threadIdx.x, lane = t & 63, wid = t >> 6;
  const int mat = blockIdx.z;
  const int n0 = blockIdx.y * 64, m0 = blockIdx.x * 64;
  const float* wm = wt + (size_t)mat * Cc * Cc;
  const float* bias = mat == 0 ? bq : (mat == 1 ? bk : bv);

  f32x4 acc[4];
#pragma unroll
  for (int f = 0; f < 4; f++) acc[f] = (f32x4){0.f, 0.f, 0.f, 0.f};

  const int srow = t >> 2, scol = (t & 3) * 16;

  for (int k0 = 0; k0 < Cc; k0 += 64) {
    const float* xs = x + (size_t)(m0 + srow) * Cc + k0 + scol;
    const float* wsrc = wm + (size_t)(n0 + srow) * Cc + k0 + scol;
#pragma unroll
    for (int j = 0; j < 16; j += 4) {
      const int off = srow * 128 + (((scol + j) * 2) ^ ((srow & 7) << 4));
      {
        float4 v = *(const float4*)(xs + j);
        unsigned h0 = bf_hi(v.x), h1 = bf_hi(v.y), h2 = bf_hi(v.z), h3 = bf_hi(v.w);
        unsigned l0 = bf_hi(v.x - bf_f(h0)), l1 = bf_hi(v.y - bf_f(h1));
        unsigned l2 = bf_hi(v.z - bf_f(h2)), l3 = bf_hi(v.w - bf_f(h3));
        *(uint2*)((char*)xh + off) = make_uint2(h0 | (h1 << 16), h2 | (h3 << 16));
        *(uint2*)((char*)xl + off) = make_uint2(l0 | (l1 << 16), l2 | (l3 << 16));
      }
      {
        float4 v = *(const float4*)(wsrc + j);
        unsigned h0 = bf_hi(v.x), h1 = bf_hi(v.y), h2 = bf_hi(v.z), h3 = bf_hi(v.w);
        unsigned l0 = bf_hi(v.x - bf_f(h0)), l1 = bf_hi(v.y - bf_f(h1));
        unsigned l2 = bf_hi(v.z - bf_f(h2)), l3 = bf_hi(v.w - bf_f(h3));
        *(uint2*)((char*)wh + off) = make_uint2(h0 | (h1 << 16), h2 | (h3 << 16));
        *(uint2*)((char*)wl + off) = make_uint2(l0 | (l1 << 16), l2 | (l3 << 16));
      }
    }
    __syncthreads();
#pragma unroll
    for (int c2 = 0; c2 < 2; c2++) {
      const int arow = wid * 16 + (lane & 15);
      const int aby = arow * 128 + ((c2 * 64 + (lane >> 4) * 16) ^ ((arow & 7) << 4));
      bf16x8 ah = *(const bf16x8*)((const char*)xh + aby);
      bf16x8 al = *(const bf16x8*)((const char*)xl + aby);
#pragma unroll
      for (int f = 0; f < 4; f++) {
        const int brow = f * 16 + (lane & 15);
        const int bby = brow * 128 + ((c2 * 64 + (lane >> 4) * 16) ^ ((brow & 7) << 4));
        bf16x8 bh = *(const bf16x8*)((const char*)wh + bby);
        bf16x8 bl = *(const bf16x8*)((const char*)wl + bby);
        acc[f] = mfma16(ah, bh, acc[f]);
        acc[f] = mfma16(al, bh, acc[f]);
        acc[f] = mfma16(ah, bl, acc[f]);
      }
    }
    __syncthreads();
  }

  const int mgbase = m0 + wid * 16 + (lane >> 4) * 4;
#pragma unroll
  for (int f = 0; f < 4; f++) {
    const int ncol = n0 + f * 16 + (lane & 15);
    const float bb = bias[ncol];
    if (mat == 0) {  // Q linear hi/lo
      unsigned short* qh = (unsigned short*)(ws + OFF_QHI);
      unsigned short* ql = (unsigned short*)(ws + OFF_QLO);
#pragma unroll
      for (int r = 0; r < 4; r++) {
        const int mg = mgbase + r;
        float v = acc[f][r] + bb;
        unsigned h = bf_hi(v);
        qh[(size_t)mg * Cc + ncol] = (unsigned short)h;
        ql[(size_t)mg * Cc + ncol] = (unsigned short)bf_hi(v - bf_f(h));
      }
    } else if (mat == 1) {  // K swizzled images hi/lo
      char* kh = ws + OFF_KHI;
      char* kl = ws + OFF_KLO;
#pragma unroll
      for (int r = 0; r < 4; r++) {
        const int mg = mgbase + r;
        const int bidx = mg >> 12, sg = mg & 4095;
        const int kt = sg >> 5, krow = sg & 31;
        const size_t base = ((size_t)(bidx * 128 + kt)) * 16384 +
                            (size_t)(krow * 512 + ((ncol * 2) ^ ((krow & 7) << 4)));
        float v = acc[f][r] + bb;
        unsigned h = bf_hi(v);
        *(unsigned short*)(kh + base) = (unsigned short)h;
        *(unsigned short*)(kl + base) = (unsigned short)bf_hi(v - bf_f(h));
      }
    } else {  // V swizzled image, hi only
      char* vh = ws + OFF_VHI;
      unsigned h[4];
#pragma unroll
      for (int r = 0; r < 4; r++) h[r] = bf_hi(acc[f][r] + bb);
      const int mg = mgbase;  // 4-aligned, within one kt tile
      const int bidx = mg >> 12, sg = mg & 4095;
      const int kt = sg >> 5, kin = sg & 31;
      const int e = ncol;
      const size_t img = (size_t)((e >> 1) * 128 +
                         (((e & 1) * 64 + kin * 2) ^ (((e >> 1) & 7) << 4)));
      *(uint2*)(vh + ((size_t)(bidx * 128 + kt)) * 16384 + img) =
          make_uint2(h[0] | (h[1] << 16), h[2] | (h[3] << 16));
    }
  }
}

// ---------------- flash attention (kv-split partials) ----------------
// grid (64 qt, B, 2 kv-half), block 256 (4 waves; wave w owns q-rows
// w*16..w*16+15, full e=256). KBLK=32, single-buffered K/V via
// global_load_lds from pre-swizzled images. 2 barriers/iter.
__global__ __launch_bounds__(256, 2) void k_attn(
    char* __restrict__ ws, float* __restrict__ out) {
  __shared__ __align__(16) char sbuf[57344];  // 0:Kh 16K:Kl 32K:Vh 48K:P(4x2K)
  const int t = threadIdx.x, lane = t & 63, w = t >> 6;
  const int qt = blockIdx.x, b = blockIdx.y, z = blockIdx.z;
  const int q0 = qt * 64;

  // ---- Q fragments (hi/lo) ----
  bf16x8 qh_[8], ql_[8];
  {
    const int qrow = q0 + w * 16 + (lane & 15);
    const unsigned short* qph =
        (const unsigned short*)(ws + OFF_QHI) + (size_t)(b * Ss + qrow) * Cc;
    const unsigned short* qpl =
        (const unsigned short*)(ws + OFF_QLO) + (size_t)(b * Ss + qrow) * Cc;
#pragma unroll
    for (int c = 0; c < 8; c++) {
      const int kb = c * 32 + (lane >> 4) * 8;
      qh_[c] = *(const bf16x8*)(qph + kb);
      ql_[c] = *(const bf16x8*)(qpl + kb);
    }
  }

  // ---- staging source offsets (linear: global layout == LDS image) ----
  unsigned srcoff[12];
#pragma unroll
  for (int j = 0; j < 12; j++) {
    const int L = w * 12288 + j * 1024;
    const int r = L >> 14, off = L & 16383;
    const unsigned rb = (r == 0 ? (unsigned)OFF_KHI
                                : (r == 1 ? (unsigned)OFF_KLO : (unsigned)OFF_VHI));
    srcoff[j] = rb + (unsigned)b * 2097152u + (unsigned)z * 1048576u +
                (unsigned)off + (unsigned)(lane * 16);
  }

  f32x4 acc[16];
#pragma unroll
  for (int eg = 0; eg < 16; eg++) acc[eg] = (f32x4){0.f, 0.f, 0.f, 0.f};
  float mrun[4] = {-1e30f, -1e30f, -1e30f, -1e30f};
  float lrun[4] = {0.f, 0.f, 0.f, 0.f};

  // ---- prologue: stage tile 0 ----
#pragma unroll
  for (int j = 0; j < 12; j++) gl16(ws + srcoff[j], sbuf + w * 12288 + j * 1024);
  __syncthreads();

  char* const phb = sbuf + 49152 + w * 2048;
  char* const plb = phb + 1024;

  for (int it = 0; it < 64; it++) {
    // ---- S = Q K^T (3-term split) ----
    f32x4 sacc[2];
    sacc[0] = (f32x4){0.f, 0.f, 0.f, 0.f};
    sacc[1] = (f32x4){0.f, 0.f, 0.f, 0.f};
    __builtin_amdgcn_s_setprio(1);
#pragma unroll
    for (int c = 0; c < 8; c++) {
#pragma unroll
      for (int f = 0; f < 2; f++) {
        const int krow = f * 16 + (lane & 15);
        const int kby = krow * 512 + ((c * 64 + (lane >> 4) * 16) ^ ((krow & 7) << 4));
        bf16x8 bh = *(const bf16x8*)(sbuf + kby);
        bf16x8 bl = *(const bf16x8*)(sbuf + 16384 + kby);
        sacc[f] = mfma16(qh_[c], bh, sacc[f]);
        sacc[f] = mfma16(ql_[c], bh, sacc[f]);
        sacc[f] = mfma16(qh_[c], bl, sacc[f]);
      }
    }
    __builtin_amdgcn_s_setprio(0);

    // ---- online softmax (row q = (lane>>4)*4+r, cols = lane&15 + f*16) ----
    float rmax[4], mnew[4], sc[4], rsum[4];
#pragma unroll
    for (int r = 0; r < 4; r++) rmax[r] = fmaxf(sacc[0][r], sacc[1][r]);
#pragma unroll
    for (int r = 0; r < 4; r++) {
      rmax[r] = fmaxf(rmax[r], __shfl_xor(rmax[r], 1, 64));
      rmax[r] = fmaxf(rmax[r], __shfl_xor(rmax[r], 2, 64));
      rmax[r] = fmaxf(rmax[r], __shfl_xor(rmax[r], 4, 64));
      rmax[r] = fmaxf(rmax[r], __shfl_xor(rmax[r], 8, 64));
      mnew[r] = fmaxf(mrun[r], rmax[r]);
      sc[r] = __expf(mrun[r] - mnew[r]);
      mrun[r] = mnew[r];
      rsum[r] = 0.f;
    }
#pragma unroll
    for (int f = 0; f < 2; f++) {
#pragma unroll
      for (int r = 0; r < 4; r++) {
        float p = __expf(sacc[f][r] - mnew[r]);
        sacc[f][r] = p;
        rsum[r] += p;
      }
    }
#pragma unroll
    for (int r = 0; r < 4; r++) {
      rsum[r] += __shfl_xor(rsum[r], 1, 64);
      rsum[r] += __shfl_xor(rsum[r], 2, 64);
      rsum[r] += __shfl_xor(rsum[r], 4, 64);
      rsum[r] += __shfl_xor(rsum[r], 8, 64);
      lrun[r] = lrun[r] * sc[r] + rsum[r];
    }

    // ---- P -> per-wave LDS (hi/lo, packed-row swizzle) ----
#pragma unroll
    for (int f = 0; f < 2; f++) {
#pragma unroll
      for (int r = 0; r < 4; r++) {
        float p = sacc[f][r];
        unsigned hb = bf_hi(p);
        unsigned lb = bf_hi(p - bf_f(hb));
        const int q = (lane >> 4) * 4 + r, kcol = f * 16 + (lane & 15);
        const int off = (q >> 1) * 128 + (((q & 1) * 64 + kcol * 2) ^ (((q >> 1) & 7) << 4));
        *(unsigned short*)(phb + off) = (unsigned short)hb;
        *(unsigned short*)(plb + off) = (unsigned short)lb;
      }
    }

    // ---- rescale O ----
#pragma unroll
    for (int eg = 0; eg < 16; eg++) {
      acc[eg][0] *= sc[0]; acc[eg][1] *= sc[1];
      acc[eg][2] *= sc[2]; acc[eg][3] *= sc[3];
    }

    // ---- O += P V (Ph*Vh + Pl*Vh) ----
    {
      const int q = lane & 15;
      const int pby = (q >> 1) * 128 +
                      (((q & 1) * 64 + (lane >> 4) * 16) ^ (((q >> 1) & 7) << 4));
      bf16x8 pa_h = *(const bf16x8*)(phb + pby);
      bf16x8 pa_l = *(const bf16x8*)(plb + pby);
      __builtin_amdgcn_s_setprio(1);
#pragma unroll
      for (int eg = 0; eg < 16; eg++) {
        const int erow = eg * 16 + (lane & 15);
        const int vby = (erow >> 1) * 128 +
                        (((erow & 1) * 64 + (lane >> 4) * 16) ^ (((erow >> 1) & 7) << 4));
        bf16x8 bvh = *(const bf16x8*)(sbuf + 32768 + vby);
        acc[eg] = mfma16(pa_h, bvh, acc[eg]);
        acc[eg] = mfma16(pa_l, bvh, acc[eg]);
      }
      __builtin_amdgcn_s_setprio(0);
    }

    __syncthreads();  // all reads of this tile done
    if (it < 63) {
#pragma unroll
      for (int j = 0; j < 12; j++) {
        srcoff[j] += 16384;
        gl16(ws + srcoff[j], sbuf + w * 12288 + j * 1024);
      }
    }
    __syncthreads();  // vmcnt(0) drain: next tile resident
  }

  // ---- epilogue: write partial (z0: f32 into out; z1: bf16) + m,l ----
  const int qloc0 = w * 16 + (lane >> 4) * 4;
  if (z == 0) {
#pragma unroll
    for (int eg = 0; eg < 16; eg++) {
      const int e = eg * 16 + (lane & 15);
#pragma unroll
      for (int r = 0; r < 4; r++)
        out[((size_t)(b * Ss + q0 + qloc0 + r)) * Ee + e] = acc[eg][r];
    }
  } else {
    unsigned short* p1 = (unsigned short*)(ws + OFF_P1);
#pragma unroll
    for (int eg = 0; eg < 16; eg++) {
      const int e = eg * 16 + (lane & 15);
#pragma unroll
      for (int r = 0; r < 4; r++)
        p1[((size_t)((b * 64 + qt) * 64 + qloc0 + r)) * 256 + e] =
            (unsigned short)bf_hi(acc[eg][r]);
    }
  }
  if ((lane & 15) == 0) {
    float* pml = (float*)(ws + OFF_PML);
#pragma unroll
    for (int r = 0; r < 4; r++) {
      const int q = qloc0 + r;
      pml[(((size_t)(z * 4 + b) * 64 + qt) * 2 + 0) * 64 + q] = mrun[r];
      pml[(((size_t)(z * 4 + b) * 64 + qt) * 2 + 1) * 64 + q] = lrun[r];
    }
  }
}

// ---------------- combine partials + sigmoid ----------------
// grid (64 qt, B), block 256 (thread = e).
__global__ __launch_bounds__(256) void k_comb(
    char* __restrict__ ws, float* __restrict__ out) {
  __shared__ float sm0[64], sl0[64], sm1[64], sl1[64];
  const int t = threadIdx.x, qt = blockIdx.x, b = blockIdx.y;
  const float* pml = (const float*)(ws + OFF_PML);
  if (t < 64) {
    sm0[t] = pml[(((size_t)(0 * 4 + b) * 64 + qt) * 2 + 0) * 64 + t];
    sl0[t] = pml[(((size_t)(0 * 4 + b) * 64 + qt) * 2 + 1) * 64 + t];
    sm1[t] = pml[(((size_t)(1 * 4 + b) * 64 + qt) * 2 + 0) * 64 + t];
    sl1[t] = pml[(((size_t)(1 * 4 + b) * 64 + qt) * 2 + 1) * 64 + t];
  }
  __syncthreads();
  const unsigned short* p1 = (const unsigned short*)(ws + OFF_P1);
  for (int q = 0; q < 64; q++) {
    const size_t o = ((size_t)(b * Ss + qt * 64 + q)) * Ee + t;
    float o0 = out[o];
    float o1 = bf_f(p1[((size_t)((b * 64 + qt) * 64 + q)) * 256 + t]);
    float M = fmaxf(sm0[q], sm1[q]);
    float a0 = __expf(sm0[q] - M), a1 = __expf(sm1[q] - M);
    float v = (o0 * a0 + o1 * a1) / (sl0[q] * a0 + sl1[q] * a1);
    out[o] = 1.f / (1.f + __expf(-v));
  }
}

extern "C" void kernel_launch(void* const* d_in, const int* in_sizes, int n_in,
                              void* d_out, int out_size, void* d_ws, size_t ws_size,
                              hipStream_t stream) {
  (void)in_sizes; (void)n_in; (void)out_size; (void)ws_size;
  const float* x  = (const float*)d_in[0];
  const float* Wq = (const float*)d_in[1];
  const float* bq = (const float*)d_in[2];
  const float* Wk = (const float*)d_in[3];
  const float* bk = (const float*)d_in[4];
  const float* Wv = (const float*)d_in[5];
  const float* bv = (const float*)d_in[6];
  float* out = (float*)d_out;
  char* ws = (char*)d_ws;
  float* wt = (float*)ws;  // 768 KB: [3][256][256] W^T

  hipLaunchKernelGGL(k_transpose, dim3(3), dim3(256), 0, stream, Wq, Wk, Wv, wt);
  hipLaunchKernelGGL(k_proj, dim3(256, 4, 3), dim3(256), 0, stream,
                     x, wt, bq, bk, bv, ws);
  hipLaunchKernelGGL(k_attn, dim3(64, Bb, 2), dim3(256), 0, stream, ws, out);
  hipLaunchKernelGGL(k_comb, dim3(64, Bb), dim3(256), 0, stream, ws, out);
}